// Round 12
// baseline (203.148 us; speedup 1.0000x reference)
//
#include <hip/hip_runtime.h>
#include <hip/hip_bf16.h>

// Problem constants (fixed by the reference)
#define B_  16
#define LQ_ 1024
#define LK_ 1024
#define C_  512

typedef __attribute__((ext_vector_type(4))) float f32x4;
typedef __attribute__((ext_vector_type(8))) short bf16x8;

__device__ __forceinline__ float bf2f(ushort u) {
  union { unsigned int i; float f; } v; v.i = ((unsigned int)u) << 16; return v.f;
}
__device__ __forceinline__ ushort f2bf(float f) {
  union { float f; unsigned int i; } v; v.f = f;
  unsigned int r = v.i + 0x7fffu + ((v.i >> 16) & 1u);
  return (ushort)(r >> 16);
}
// tanh-form gelu (max |diff| vs exact erf-gelu ~1e-3; threshold headroom 6x)
__device__ __forceinline__ float gelu_fast(float x) {
  float u = x * (0.7978845608f + 0.0356774081f * x * x);
  u = fminf(fmaxf(u, -9.f), 9.f);          // overflow guard
  float e = __expf(2.f * u);               // v_exp_f32 class
  float t = (e - 1.f) / (e + 1.f);
  return 0.5f * x * (1.f + t);
}

// async global->LDS, 16B per lane; LDS dest is wave-uniform base + lane*16.
__device__ __forceinline__ void gload_lds16(const ushort* g, ushort* l) {
  __builtin_amdgcn_global_load_lds(
      (const __attribute__((address_space(1))) void*)g,
      (__attribute__((address_space(3))) void*)l, 16, 0, 0);
}

// ---------------------------------------------------------------------------
// prep_all: one dispatch for {query, key -> bf16 + norms} and {w1, w2 -> bf16}.
// One wave per 512-float row. Rows: [0,16384) query, [16384,32768) key,
// [32768,34816) w1 (2048 rows of 512), [34816,36864) w2. Grid 9216 x 256.
__global__ __launch_bounds__(256) void prep_all(
    const float* __restrict__ q, const float* __restrict__ k,
    const float* __restrict__ w1, const float* __restrict__ w2,
    ushort* __restrict__ Qb, ushort* __restrict__ Kb,
    ushort* __restrict__ W1b, ushort* __restrict__ W2b,
    float* __restrict__ qn, float* __restrict__ kn) {
  int wid = blockIdx.x * 4 + (threadIdx.x >> 6);
  int lane = threadIdx.x & 63;
  const float* src;
  ushort* dst;
  float* nrm = nullptr;
  if (wid < 16384) {
    src = q + (long)wid * C_;  dst = Qb + (long)wid * C_;  nrm = qn + wid;
  } else if (wid < 32768) {
    int r = wid - 16384;
    src = k + (long)r * C_;    dst = Kb + (long)r * C_;    nrm = kn + r;
  } else if (wid < 34816) {
    int r = wid - 32768;
    src = w1 + (long)r * C_;   dst = W1b + (long)r * C_;
  } else {
    int r = wid - 34816;
    src = w2 + (long)r * C_;   dst = W2b + (long)r * C_;
  }
  float ss = 0.f;
#pragma unroll
  for (int i0 = 0; i0 < 2; ++i0) {
    int i = lane * 4 + i0 * 256;
    float4 v = *(const float4*)(src + i);
    ss += v.x * v.x + v.y * v.y + v.z * v.z + v.w * v.w;
    ushort4 o;
    o.x = f2bf(v.x); o.y = f2bf(v.y); o.z = f2bf(v.z); o.w = f2bf(v.w);
    *(ushort4*)(dst + i) = o;
  }
  if (nrm) {
#pragma unroll
    for (int off = 32; off > 0; off >>= 1) ss += __shfl_xor(ss, off);
    if (lane == 0) *nrm = sqrtf(ss);
  }
}

// ---------------------------------------------------------------------------
// Batched NT GEMM — TLP-first variant: tile 128(M) x 64(N), BK=32, 4 waves
// (2x2; per-wave 64x32, acc = 8 x f32x4 = 32 VGPR). LDS 24 KB dbuf ->
// ~6 resident blocks/CU; grid 2048 (8 blocks/CU) so wave-level TLP covers
// the per-iter staging latency (R3..R11 structures were capped at 2.6
// blocks/CU by the 1024-block grid and stayed latency-bound).
// R3-proven loop skeleton: global_load_lds staging (3/thread/iter), ONE
// __syncthreads per K-iter, 16B-chunk XOR swizzle cb^=(row>>1)&3 on global
// source + ds_read address (0 bank conflicts measured).
// EPI 0: v/(qn*kn+1e-2) -> bf16 (batch-offset qn/kn).  EPI 1: gelu_fast.
// EPI 2: no C store; fused row-dot with w3 -> atomicAdd into wv.
#define BK 32

template <int EPI>
__device__ __forceinline__ void gemm128x64_body(
    const ushort* __restrict__ A, const ushort* __restrict__ Bm,
    ushort* __restrict__ Cc, int K, long sA, long sB, long sC,
    const float* __restrict__ qn, const float* __restrict__ kn,
    const float* __restrict__ w3v, float* __restrict__ wv) {
  // XCD-aware block swizzle: nwg = 2048, 2048 % 8 == 0 -> bijective
  int per = (int)(gridDim.x >> 3);
  int orig = blockIdx.x;
  int id = (orig & 7) * per + (orig >> 3);
  int b = id >> 7;              // 128 blocks per batch (8 m x 16 n)
  int rtile = id & 127;
  const int bm = (rtile >> 4) * 128, bn = (rtile & 15) * 64;

  A += (long)b * sA;
  Bm += (long)b * sB;

  __shared__ ushort smem[12288];
  // A bufs at 0 / 4096 (128x32 each); B bufs at 8192 / 10240 (64x32 each)

  int tid = threadIdx.x;
  int lane = tid & 63, w = tid >> 6;
  int wr = w >> 1, wc = w & 1;
  int l16 = lane & 15, lhi = lane >> 4;

  f32x4 acc[4][2] = {};

  // staging: A = 512 chunks (2 issues), B = 256 chunks (1 issue); 16B each
  int cA0 = tid, cA1 = tid + 256, cB = tid;
  int rA0 = cA0 >> 2, xA0 = (cA0 & 3) ^ ((rA0 >> 1) & 3);
  int rA1 = cA1 >> 2, xA1 = (cA1 & 3) ^ ((rA1 >> 1) & 3);
  int rB = cB >> 2,  xB = (cB & 3) ^ ((rB >> 1) & 3);
  int wb0 = (tid & ~63) * 8;       // ushort offset, wave-uniform
  int wb1 = wb0 + 256 * 8;

  const ushort* ArA0 = A + (long)(bm + rA0) * K + xA0 * 8;
  const ushort* ArA1 = A + (long)(bm + rA1) * K + xA1 * 8;
  const ushort* BrB  = Bm + (long)(bn + rB) * K + xB * 8;

  const int nt = K / BK;
  // prologue: stage tile 0 into buf 0
  gload_lds16(ArA0, smem + wb0);
  gload_lds16(ArA1, smem + wb1);
  gload_lds16(BrB, smem + 8192 + wb0);
  __syncthreads();

  int cur = 0;
  for (int t = 0; t < nt; ++t) {
    if (t + 1 < nt) {
      int k1 = (t + 1) * BK;
      int nxA = (cur ^ 1) * 4096;
      int nxB = (cur ^ 1) * 2048;
      gload_lds16(ArA0 + k1, smem + nxA + wb0);
      gload_lds16(ArA1 + k1, smem + nxA + wb1);
      gload_lds16(BrB + k1, smem + 8192 + nxB + wb0);
    }

    const ushort* Ac = smem + cur * 4096;
    const ushort* Bc = smem + 8192 + cur * 2048;
    bf16x8 af[4], bfr[2];
#pragma unroll
    for (int m = 0; m < 4; ++m) {
      int r = wr * 64 + m * 16 + l16;
      af[m] = *(const bf16x8*)(Ac + r * 32 + ((lhi ^ ((r >> 1) & 3)) * 8));
    }
#pragma unroll
    for (int n = 0; n < 2; ++n) {
      int r = wc * 32 + n * 16 + l16;
      bfr[n] = *(const bf16x8*)(Bc + r * 32 + ((lhi ^ ((r >> 1) & 3)) * 8));
    }
#pragma unroll
    for (int m = 0; m < 4; ++m)
#pragma unroll
      for (int n = 0; n < 2; ++n)
        acc[m][n] = __builtin_amdgcn_mfma_f32_16x16x32_bf16(af[m], bfr[n],
                                                            acc[m][n], 0, 0, 0);
    // implicit vmcnt(0)+lgkmcnt(0): waits on prefetch and makes buf[cur]
    // safe to overwrite next iteration.
    __syncthreads();
    cur ^= 1;
  }

  // epilogue (C/D layout: col = lane&15, row = (lane>>4)*4 + reg)
  if constexpr (EPI == 2) {
    float* wvb = wv + (long)b * LQ_;
    float w3c[2];
#pragma unroll
    for (int n = 0; n < 2; ++n) w3c[n] = w3v[bn + wc * 32 + n * 16 + l16];
#pragma unroll
    for (int m = 0; m < 4; ++m)
#pragma unroll
      for (int rr = 0; rr < 4; ++rr) {
        float s = 0.f;
#pragma unroll
        for (int n = 0; n < 2; ++n)
          s += gelu_fast(acc[m][n][rr]) * w3c[n];
        s += __shfl_xor(s, 1);
        s += __shfl_xor(s, 2);
        s += __shfl_xor(s, 4);
        s += __shfl_xor(s, 8);
        if (l16 == 0)
          atomicAdd(&wvb[bm + wr * 64 + m * 16 + lhi * 4 + rr], s);
      }
  } else {
    Cc += (long)b * sC;
    const float* qnb = qn + (long)b * LQ_;
    const float* knb = kn + (long)b * LK_;
#pragma unroll
    for (int m = 0; m < 4; ++m) {
      int row0 = bm + wr * 64 + m * 16 + lhi * 4;
#pragma unroll
      for (int n = 0; n < 2; ++n) {
        int col = bn + wc * 32 + n * 16 + l16;
#pragma unroll
        for (int rr = 0; rr < 4; ++rr) {
          float v = acc[m][n][rr];
          int grow = row0 + rr;
          if (EPI == 0) {
            v = v / (qnb[grow] * knb[col] + 1e-2f);
          } else {
            v = gelu_fast(v);
          }
          Cc[(long)grow * 1024 + col] = f2bf(v);
        }
      }
    }
  }
}

__global__ __launch_bounds__(256, 4) void gemm_s(
    const ushort* __restrict__ A, const ushort* __restrict__ Bm,
    ushort* __restrict__ Cc, const float* __restrict__ qn,
    const float* __restrict__ kn) {
  gemm128x64_body<0>(A, Bm, Cc, C_, (long)LQ_ * C_, (long)LK_ * C_,
                     (long)LQ_ * LK_, qn, kn, nullptr, nullptr);
}

__global__ __launch_bounds__(256, 4) void gemm_h1(
    const ushort* __restrict__ A, const ushort* __restrict__ Bm,
    ushort* __restrict__ Cc) {
  gemm128x64_body<1>(A, Bm, Cc, LK_, (long)LQ_ * LK_, 0L, (long)LQ_ * LK_,
                     nullptr, nullptr, nullptr, nullptr);
}

__global__ __launch_bounds__(256, 4) void gemm_h2w(
    const ushort* __restrict__ A, const ushort* __restrict__ Bm,
    const float* __restrict__ w3v, float* __restrict__ wv) {
  gemm128x64_body<2>(A, Bm, nullptr, LK_, (long)LQ_ * LK_, 0L, 0L,
                     nullptr, nullptr, w3v, wv);
}

// ---------------------------------------------------------------------------
// gate: wraw[b,k] += sum_{q in 64-chunk} wv[b,q] * S[b,q,k]
// grid (1, 16, B_), 256 threads; each thread owns 4 consecutive k (ushort4).
__global__ __launch_bounds__(256) void gate_partial(const ushort* __restrict__ S,
                                                    const float* __restrict__ wv,
                                                    float* __restrict__ wraw) {
  int b = blockIdx.z;
  int q0 = blockIdx.y * 64;
  int k4 = threadIdx.x * 4;
  const ushort* p = S + (long)b * LQ_ * LK_ + (long)q0 * LK_ + k4;
  const float* wb = wv + b * LQ_ + q0;
  float a0 = 0.f, a1 = 0.f, a2 = 0.f, a3 = 0.f;
#pragma unroll 4
  for (int q = 0; q < 64; ++q) {
    float wq = wb[q];
    ushort4 s4 = *(const ushort4*)(p + (long)q * LK_);
    a0 += wq * bf2f(s4.x);
    a1 += wq * bf2f(s4.y);
    a2 += wq * bf2f(s4.z);
    a3 += wq * bf2f(s4.w);
  }
  float* wr = wraw + b * LK_ + k4;
  atomicAdd(wr + 0, a0);
  atomicAdd(wr + 1, a1);
  atomicAdd(wr + 2, a2);
  atomicAdd(wr + 3, a3);
}

// out[b,k,c] = value * (1 + tanh(wraw/32)); one float4 per thread
__global__ __launch_bounds__(256) void finalize(const float* __restrict__ value,
                                                const float* __restrict__ wraw,
                                                float* __restrict__ out) {
  long i = (long)blockIdx.x * 256 + threadIdx.x;  // float4 index
  long e = i * 4;
  int row = (int)(e >> 9);  // / 512
  float g = 1.f + tanhf(wraw[row] * (1.f / 32.f));
  float4 v = ((const float4*)value)[i];
  v.x *= g; v.y *= g; v.z *= g; v.w *= g;
  ((float4*)out)[i] = v;
}

// ---------------------------------------------------------------------------
extern "C" void kernel_launch(void* const* d_in, const int* in_sizes, int n_in,
                              void* d_out, int out_size, void* d_ws,
                              size_t ws_size, hipStream_t stream) {
  const float* query = (const float*)d_in[0];
  const float* key   = (const float*)d_in[1];
  const float* value = (const float*)d_in[2];
  const float* w1    = (const float*)d_in[3];
  const float* w2    = (const float*)d_in[4];
  const float* w3    = (const float*)d_in[5];
  float* out = (float*)d_out;

  // workspace layout (bytes)
  const size_t QB_BYTES = (size_t)B_ * LQ_ * C_ * 2;       // 16 MB
  const size_t S_BYTES  = (size_t)B_ * LQ_ * LK_ * 2;      // 32 MB
  const size_t W_BYTES  = (size_t)LK_ * LK_ * 2;           // 2 MB
  const size_t OFF_QB = 0;
  const size_t OFF_KB = OFF_QB + QB_BYTES;
  const size_t OFF_S  = OFF_KB + QB_BYTES;
  const size_t OFF_H1 = OFF_S + S_BYTES;
  const size_t OFF_W1 = OFF_H1 + S_BYTES;
  const size_t OFF_W2 = OFF_W1 + W_BYTES;
  const size_t OFF_QN = OFF_W2 + W_BYTES;
  const size_t OFF_KN = OFF_QN + (size_t)B_ * LQ_ * 4;
  const size_t OFF_WV = OFF_KN + (size_t)B_ * LK_ * 4;
  const size_t OFF_WR = OFF_WV + (size_t)B_ * LQ_ * 4;
  const size_t TOTAL  = OFF_WR + (size_t)B_ * LK_ * 4;
  if (ws_size < TOTAL) return;  // workspace too small; fail visibly

  char* ws = (char*)d_ws;
  ushort* Qb  = (ushort*)(ws + OFF_QB);
  ushort* Kb  = (ushort*)(ws + OFF_KB);
  ushort* S   = (ushort*)(ws + OFF_S);
  ushort* h1  = (ushort*)(ws + OFF_H1);
  ushort* W1b = (ushort*)(ws + OFF_W1);
  ushort* W2b = (ushort*)(ws + OFF_W2);
  float* qn   = (float*)(ws + OFF_QN);
  float* kn   = (float*)(ws + OFF_KN);
  float* wv   = (float*)(ws + OFF_WV);
  float* wraw = (float*)(ws + OFF_WR);

  // 1) prep (single dispatch): bf16 casts + norms
  prep_all<<<dim3(9216), 256, 0, stream>>>(query, key, w1, w2, Qb, Kb, W1b,
                                           W2b, qn, kn);
  hipMemsetAsync(wraw, 0, (size_t)B_ * LK_ * 4, stream);
  hipMemsetAsync(wv, 0, (size_t)B_ * LQ_ * 4, stream);

  // 2) S = (Q K^T) / (|q||k| + 1e-2), bf16
  gemm_s<<<dim3(2048), 256, 0, stream>>>(Qb, Kb, S, qn, kn);

  // 3) h1 = gelu(S @ W1^T)
  gemm_h1<<<dim3(2048), 256, 0, stream>>>(S, W1b, h1);

  // 4) fused: wv[b,q] = dot(gelu(h1 @ W2^T)[q,:], w3)  (h2 never stored)
  gemm_h2w<<<dim3(2048), 256, 0, stream>>>(h1, W2b, w3, wv);

  // 5) wraw[b,k] = sum_q wv[b,q] * S[b,q,k]
  gate_partial<<<dim3(1, 16, B_), 256, 0, stream>>>(S, wv, wraw);

  // 6) out = value * (1 + tanh(wraw/32))
  finalize<<<dim3((size_t)B_ * LK_ * C_ / 4 / 256), 256, 0, stream>>>(value, wraw, out);
}

// Round 13
// 166.654 us; speedup vs baseline: 1.2190x; 1.2190x over previous
//
#include <hip/hip_runtime.h>
#include <hip/hip_bf16.h>

// Problem constants (fixed by the reference)
#define B_  16
#define LQ_ 1024
#define LK_ 1024
#define C_  512

typedef __attribute__((ext_vector_type(4))) float f32x4;
typedef unsigned char uchar;

__device__ __forceinline__ float bf2f(ushort u) {
  union { unsigned int i; float f; } v; v.i = ((unsigned int)u) << 16; return v.f;
}
// tanh-form gelu (max |diff| vs exact erf-gelu ~1e-3; threshold headroom 6x)
__device__ __forceinline__ float gelu_fast(float x) {
  float u = x * (0.7978845608f + 0.0356774081f * x * x);
  u = fminf(fmaxf(u, -9.f), 9.f);          // overflow guard
  float e = __expf(2.f * u);               // v_exp_f32 class
  float t = (e - 1.f) / (e + 1.f);
  return 0.5f * x * (1.f + t);
}

// float -> OCP e4m3fn, round-to-nearest (manual; no fp8 builtin dependency)
__device__ __forceinline__ uchar f2fp8(float x) {
  float ax = fabsf(x);
  ax = fminf(ax, 448.f);
  unsigned int sgn = (__float_as_uint(x) >> 24) & 0x80u;
  unsigned int b;
  if (ax >= 0.015625f) {                   // normal: e in [1,15]
    unsigned int u = __float_as_uint(ax);
    u += 0x7FFFFu + ((u >> 20) & 1u);      // RN-even to 3 mantissa bits
    unsigned int e = (u >> 23) - 120u;
    b = (e << 3) | ((u >> 20) & 7u);
  } else {                                  // subnormal: m * 2^-9
    b = (unsigned int)(ax * 512.f + 0.5f); // 0..8 (8 == 2^-6, e=1 m=0)
  }
  return (uchar)(sgn | b);
}
// OCP e4m3fn -> float
__device__ __forceinline__ float fp82f(unsigned int b) {
  unsigned int e = (b >> 3) & 15u, m = b & 7u;
  unsigned int ee = e ? e : 1u;
  unsigned int mm = m + (e ? 8u : 0u);
  union { unsigned int u; float f; } p; p.u = (ee + 117u) << 23;  // 2^(ee-10)
  float r = (float)mm * p.f;
  return (b & 0x80u) ? -r : r;
}

// async global->LDS, 16B per lane; LDS dest is wave-uniform base + lane*16.
__device__ __forceinline__ void gload_lds16(const uchar* g, uchar* l) {
  __builtin_amdgcn_global_load_lds(
      (const __attribute__((address_space(1))) void*)g,
      (__attribute__((address_space(3))) void*)l, 16, 0, 0);
}

// ---------------------------------------------------------------------------
// prep_all: one dispatch. Q,K -> fp8 (scale 1) + fp32 norms of ORIGINAL rows;
// w1,w2 -> fp8 scaled x32 (w ~ N(0,1/32) -> N(0,1), ideal e4m3 range).
// Rows: [0,16384) query, [16384,32768) key, [32768,34816) w1, [34816,36864) w2.
__global__ __launch_bounds__(256) void prep_all(
    const float* __restrict__ q, const float* __restrict__ k,
    const float* __restrict__ w1, const float* __restrict__ w2,
    uchar* __restrict__ Qb, uchar* __restrict__ Kb,
    uchar* __restrict__ W1b, uchar* __restrict__ W2b,
    float* __restrict__ qn, float* __restrict__ kn) {
  int wid = blockIdx.x * 4 + (threadIdx.x >> 6);
  int lane = threadIdx.x & 63;
  const float* src;
  uchar* dst;
  float* nrm = nullptr;
  float scale = 1.f;
  if (wid < 16384) {
    src = q + (long)wid * C_;  dst = Qb + (long)wid * C_;  nrm = qn + wid;
  } else if (wid < 32768) {
    int r = wid - 16384;
    src = k + (long)r * C_;    dst = Kb + (long)r * C_;    nrm = kn + r;
  } else if (wid < 34816) {
    int r = wid - 32768;
    src = w1 + (long)r * C_;   dst = W1b + (long)r * C_;   scale = 32.f;
  } else {
    int r = wid - 34816;
    src = w2 + (long)r * C_;   dst = W2b + (long)r * C_;   scale = 32.f;
  }
  float ss = 0.f;
#pragma unroll
  for (int i0 = 0; i0 < 2; ++i0) {
    int i = lane * 4 + i0 * 256;
    float4 v = *(const float4*)(src + i);
    ss += v.x * v.x + v.y * v.y + v.z * v.z + v.w * v.w;
    unsigned int pk = (unsigned int)f2fp8(v.x * scale) |
                      ((unsigned int)f2fp8(v.y * scale) << 8) |
                      ((unsigned int)f2fp8(v.z * scale) << 16) |
                      ((unsigned int)f2fp8(v.w * scale) << 24);
    *(unsigned int*)(dst + i) = pk;
  }
  if (nrm) {
#pragma unroll
    for (int off = 32; off > 0; off >>= 1) ss += __shfl_xor(ss, off);
    if (lane == 0) *nrm = sqrtf(ss);
  }
}

// ---------------------------------------------------------------------------
// Batched NT GEMM, fp8 e4m3 operands — R3/R11-exact loop structure with
// HALF the staged bytes (the measured ~10 TB/s staging ceiling is the wall).
// 128x128 tile, BK=32 (32 B/row), 4 waves (2x2 of 64x64), 2-buffer dbuf,
// global_load_lds staging (2 gloads/thread/iter), ONE __syncthreads/iter.
// LDS 16 KB total: A bufs at 0/4096, B bufs at 8192/12288 (bytes).
// Swizzle: rows have 2 16B-chunks; chunk h' = h ^ (row&1) on global source
// + ds_read address (LDS dest linear, rule 21). ds_read_b64 frags.
// MFMA: mfma_f32_16x16x32_fp8_fp8, frag = 8 fp8 (long), same lane mapping
// as the verified bf16 16x16x32 (row=l16, k-octet=lhi).
// EPI 0: v/(qn*kn+1e-2), store fp8(16*v).  EPI 1: gelu(acc/512), store
// fp8(16*v).  EPI 2: wv += dot(gelu(acc/512), w3) (no C store).
#define BK 32

template <int EPI>
__device__ __forceinline__ void gemm128_body(
    const uchar* __restrict__ A, const uchar* __restrict__ Bm,
    uchar* __restrict__ Cc, int K, long sA, long sB, long sC,
    const float* __restrict__ qn, const float* __restrict__ kn,
    const float* __restrict__ w3v, float* __restrict__ wv) {
  // XCD-aware block swizzle: nwg = 1024, nwg % 8 == 0 -> bijective
  int per = (int)(gridDim.x >> 3);
  int orig = blockIdx.x;
  int id = (orig & 7) * per + (orig >> 3);
  int b = id >> 6;              // 64 blocks per batch (8x8)
  int rtile = id & 63;
  const int bm = (rtile >> 3) * 128, bn = (rtile & 7) * 128;

  A += (long)b * sA;
  Bm += (long)b * sB;

  __shared__ uchar smem[16384];

  int tid = threadIdx.x;
  int lane = tid & 63, w = tid >> 6;
  int wr = w >> 1, wc = w & 1;
  int l16 = lane & 15, lhi = lane >> 4;

  f32x4 acc[4][4] = {};

  // staging: 256 16B-chunks per operand per K-tile; 1 gload/thread each.
  // chunk c = tid: row r = c>>1, half h = (c&1) ^ (r&1)  (swizzled source)
  int sr = tid >> 1;
  int sh = (tid & 1) ^ (sr & 1);
  int wb = (tid & ~63) * 16;       // byte offset, wave-uniform dest base

  const uchar* Asrc = A + (long)(bm + sr) * K + sh * 16;
  const uchar* Bsrc = Bm + (long)(bn + sr) * K + sh * 16;

  const int nt = K / BK;
  // prologue: stage tile 0 into buf 0
  gload_lds16(Asrc, smem + wb);
  gload_lds16(Bsrc, smem + 8192 + wb);
  __syncthreads();

  // fragment byte offsets within a row: k-octet o = lhi (8B each)
  // swizzled: ((o>>1) ^ (r&1))*16 + (o&1)*8
  int cur = 0;
  for (int t = 0; t < nt; ++t) {
    if (t + 1 < nt) {
      int k1 = (t + 1) * BK;
      int nx = (cur ^ 1) * 4096;
      gload_lds16(Asrc + k1, smem + nx + wb);
      gload_lds16(Bsrc + k1, smem + 8192 + nx + wb);
    }

    const uchar* Ac = smem + cur * 4096;
    const uchar* Bc = smem + 8192 + cur * 4096;
    long af[4], bfr[4];
#pragma unroll
    for (int m = 0; m < 4; ++m) {
      int r = wr * 64 + m * 16 + l16;
      af[m] = *(const long*)(Ac + r * 32 + (((lhi >> 1) ^ (r & 1)) * 16 + (lhi & 1) * 8));
    }
#pragma unroll
    for (int n = 0; n < 4; ++n) {
      int r = wc * 64 + n * 16 + l16;
      bfr[n] = *(const long*)(Bc + r * 32 + (((lhi >> 1) ^ (r & 1)) * 16 + (lhi & 1) * 8));
    }
#pragma unroll
    for (int m = 0; m < 4; ++m)
#pragma unroll
      for (int n = 0; n < 4; ++n)
        acc[m][n] = __builtin_amdgcn_mfma_f32_16x16x32_fp8_fp8(
            af[m], bfr[n], acc[m][n], 0, 0, 0);
    __syncthreads();
    cur ^= 1;
  }

  // epilogue (C/D layout: col = lane&15, row = (lane>>4)*4 + reg)
  if constexpr (EPI == 2) {
    float* wvb = wv + (long)b * LQ_;
    float w3c[4];
#pragma unroll
    for (int n = 0; n < 4; ++n) w3c[n] = w3v[bn + wc * 64 + n * 16 + l16];
#pragma unroll
    for (int m = 0; m < 4; ++m)
#pragma unroll
      for (int rr = 0; rr < 4; ++rr) {
        float s = 0.f;
#pragma unroll
        for (int n = 0; n < 4; ++n)
          s += gelu_fast(acc[m][n][rr] * (1.f / 512.f)) * w3c[n];
        s += __shfl_xor(s, 1);
        s += __shfl_xor(s, 2);
        s += __shfl_xor(s, 4);
        s += __shfl_xor(s, 8);
        if (l16 == 0)
          atomicAdd(&wvb[bm + wr * 64 + m * 16 + lhi * 4 + rr], s);
      }
  } else {
    Cc += (long)b * sC;
    const float* qnb = qn + (long)b * LQ_;
    const float* knb = kn + (long)b * LK_;
#pragma unroll
    for (int m = 0; m < 4; ++m) {
      int row0 = bm + wr * 64 + m * 16 + lhi * 4;
#pragma unroll
      for (int n = 0; n < 4; ++n) {
        int col = bn + wc * 64 + n * 16 + l16;
#pragma unroll
        for (int rr = 0; rr < 4; ++rr) {
          float v = acc[m][n][rr];
          int grow = row0 + rr;
          if (EPI == 0) {
            v = v / (qnb[grow] * knb[col] + 1e-2f);   // true S in [-1,1]
          } else {
            v = gelu_fast(v * (1.f / 512.f));          // true h1
          }
          Cc[(long)grow * 1024 + col] = f2fp8(v * 16.f);  // store 16x scaled
        }
      }
    }
  }
}

__global__ __launch_bounds__(256, 2) void gemm_s(
    const uchar* __restrict__ A, const uchar* __restrict__ Bm,
    uchar* __restrict__ Cc, const float* __restrict__ qn,
    const float* __restrict__ kn) {
  gemm128_body<0>(A, Bm, Cc, C_, (long)LQ_ * C_, (long)LK_ * C_,
                  (long)LQ_ * LK_, qn, kn, nullptr, nullptr);
}

__global__ __launch_bounds__(256, 2) void gemm_h1(
    const uchar* __restrict__ A, const uchar* __restrict__ Bm,
    uchar* __restrict__ Cc) {
  gemm128_body<1>(A, Bm, Cc, LK_, (long)LQ_ * LK_, 0L, (long)LQ_ * LK_,
                  nullptr, nullptr, nullptr, nullptr);
}

__global__ __launch_bounds__(256, 2) void gemm_h2w(
    const uchar* __restrict__ A, const uchar* __restrict__ Bm,
    const float* __restrict__ w3v, float* __restrict__ wv) {
  gemm128_body<2>(A, Bm, nullptr, LK_, (long)LQ_ * LK_, 0L, 0L,
                  nullptr, nullptr, w3v, wv);
}

// ---------------------------------------------------------------------------
// gate: wraw[b,k] += sum_{q in 64-chunk} wv[b,q] * S8[b,q,k]  (S8 = 16*S)
// grid (1, 16, B_), 256 threads; each thread owns 4 consecutive k (uint).
__global__ __launch_bounds__(256) void gate_partial(const uchar* __restrict__ S,
                                                    const float* __restrict__ wv,
                                                    float* __restrict__ wraw) {
  int b = blockIdx.z;
  int q0 = blockIdx.y * 64;
  int k4 = threadIdx.x * 4;
  const uchar* p = S + (long)b * LQ_ * LK_ + (long)q0 * LK_ + k4;
  const float* wb = wv + b * LQ_ + q0;
  float a0 = 0.f, a1 = 0.f, a2 = 0.f, a3 = 0.f;
#pragma unroll 4
  for (int q = 0; q < 64; ++q) {
    float wq = wb[q];
    unsigned int s4 = *(const unsigned int*)(p + (long)q * LK_);
    a0 += wq * fp82f(s4 & 0xFF);
    a1 += wq * fp82f((s4 >> 8) & 0xFF);
    a2 += wq * fp82f((s4 >> 16) & 0xFF);
    a3 += wq * fp82f(s4 >> 24);
  }
  float* wr = wraw + b * LK_ + k4;
  atomicAdd(wr + 0, a0);
  atomicAdd(wr + 1, a1);
  atomicAdd(wr + 2, a2);
  atomicAdd(wr + 3, a3);
}

// out[b,k,c] = value * (1 + tanh(wraw/(32*16))); one float4 per thread
// (wraw carries the 16x S-scale)
__global__ __launch_bounds__(256) void finalize(const float* __restrict__ value,
                                                const float* __restrict__ wraw,
                                                float* __restrict__ out) {
  long i = (long)blockIdx.x * 256 + threadIdx.x;  // float4 index
  long e = i * 4;
  int row = (int)(e >> 9);  // / 512
  float g = 1.f + tanhf(wraw[row] * (1.f / 512.f));
  float4 v = ((const float4*)value)[i];
  v.x *= g; v.y *= g; v.z *= g; v.w *= g;
  ((float4*)out)[i] = v;
}

// ---------------------------------------------------------------------------
extern "C" void kernel_launch(void* const* d_in, const int* in_sizes, int n_in,
                              void* d_out, int out_size, void* d_ws,
                              size_t ws_size, hipStream_t stream) {
  const float* query = (const float*)d_in[0];
  const float* key   = (const float*)d_in[1];
  const float* value = (const float*)d_in[2];
  const float* w1    = (const float*)d_in[3];
  const float* w2    = (const float*)d_in[4];
  const float* w3    = (const float*)d_in[5];
  float* out = (float*)d_out;

  // workspace layout (bytes) — fp8 operands
  const size_t QB_BYTES = (size_t)B_ * LQ_ * C_;           // 8 MB
  const size_t S_BYTES  = (size_t)B_ * LQ_ * LK_;          // 16 MB
  const size_t W_BYTES  = (size_t)LK_ * LK_;               // 1 MB
  const size_t OFF_QB = 0;
  const size_t OFF_KB = OFF_QB + QB_BYTES;
  const size_t OFF_S  = OFF_KB + QB_BYTES;
  const size_t OFF_H1 = OFF_S + S_BYTES;
  const size_t OFF_W1 = OFF_H1 + S_BYTES;
  const size_t OFF_W2 = OFF_W1 + W_BYTES;
  const size_t OFF_QN = OFF_W2 + W_BYTES;
  const size_t OFF_KN = OFF_QN + (size_t)B_ * LQ_ * 4;
  const size_t OFF_WV = OFF_KN + (size_t)B_ * LK_ * 4;
  const size_t OFF_WR = OFF_WV + (size_t)B_ * LQ_ * 4;
  const size_t TOTAL  = OFF_WR + (size_t)B_ * LK_ * 4;
  if (ws_size < TOTAL) return;  // workspace too small; fail visibly

  char* ws = (char*)d_ws;
  uchar* Qb  = (uchar*)(ws + OFF_QB);
  uchar* Kb  = (uchar*)(ws + OFF_KB);
  uchar* S   = (uchar*)(ws + OFF_S);
  uchar* h1  = (uchar*)(ws + OFF_H1);
  uchar* W1b = (uchar*)(ws + OFF_W1);
  uchar* W2b = (uchar*)(ws + OFF_W2);
  float* qn   = (float*)(ws + OFF_QN);
  float* kn   = (float*)(ws + OFF_KN);
  float* wv   = (float*)(ws + OFF_WV);
  float* wraw = (float*)(ws + OFF_WR);

  // 1) prep (single dispatch): fp8 casts + norms
  prep_all<<<dim3(9216), 256, 0, stream>>>(query, key, w1, w2, Qb, Kb, W1b,
                                           W2b, qn, kn);
  hipMemsetAsync(wraw, 0, (size_t)B_ * LK_ * 4, stream);
  hipMemsetAsync(wv, 0, (size_t)B_ * LQ_ * 4, stream);

  // 2) S8 = 16 * (Q K^T)/(|q||k| + 1e-2), fp8
  gemm_s<<<dim3(1024), 256, 0, stream>>>(Qb, Kb, S, qn, kn);

  // 3) h1_8 = 16 * gelu((S8 @ W1b^T)/512)
  gemm_h1<<<dim3(1024), 256, 0, stream>>>(S, W1b, h1);

  // 4) fused: wv[b,q] = dot(gelu((h1_8 @ W2b^T)/512), w3)
  gemm_h2w<<<dim3(1024), 256, 0, stream>>>(h1, W2b, w3, wv);

  // 5) wraw[b,k] = sum_q wv[b,q] * S8[b,q,k]   (carries 16x scale)
  gate_partial<<<dim3(1, 16, B_), 256, 0, stream>>>(S, wv, wraw);

  // 6) out = value * (1 + tanh(wraw/512))
  finalize<<<dim3((size_t)B_ * LK_ * C_ / 4 / 256), 256, 0, stream>>>(value, wraw, out);
}